// Round 6
// baseline (96.548 us; speedup 1.0000x reference)
//
#include <hip/hip_runtime.h>
#include <math.h>

// ParabolicPool2D: morphological dilation (max-plus pool), KS=7, STRIDE=2, pad=3.
// Separable in max-plus: h[c,ki,kj] = g[c,ki] + g[c,kj], g[c,j] = -z_j^2/(4 t_c),
// z = linspace(-2, 3, 7)  =>  out = max_ki( max_kj(f + g_kj) + g_ki ).
//
// R6: TH 8 -> 16. Each thread owns TW=4 output cols x TH=16 output rows with a
// rolling vertical max-plus window. Vertical row overfetch: 37 input rows read
// per 32 advanced = 1.156x (R5 was 21/16 = 1.31x, R4 was 2.25x).
// Full unroll keeps all indexing static; at most 4 acc-rows are live at any r
// (ki = r-2d in [0,6]), so VGPR liveness does NOT grow with TH.
// __launch_bounds__(256,4) caps VGPR at 128 so the demanded 4.6 waves/SIMD
// can be resident (grid = 301,056 threads = 4704 waves).

#define KS     7
#define C_CH   96
#define B_SZ   16
#define H_IN   224
#define W_IN   224
#define H_OUT  112
#define W_OUT  112
#define TW     4                 // output cols per thread
#define TH     16                // output rows per thread
#define KX     (W_OUT / TW)      // 28
#define KYV    (H_OUT / TH)      // 7
#define NROWS  (2 * TH + 5)      // 37 input rows per strip

__global__ __launch_bounds__(256, 4)
void parab_pool2d_kernel(const float* __restrict__ f,
                         const float* __restrict__ t,
                         float* __restrict__ out)
{
    const int idx = blockIdx.x * 256 + threadIdx.x;
    const int k   = idx % KX;
    const int tyv = (idx / KX) % KYV;
    const int c   = (idx / (KX * KYV)) % C_CH;
    const int b   =  idx / (KX * KYV * C_CH);

    // g[j] = -z_j^2 / (4 t_c),  z = -2 + j*(5/6)
    const float s = 1.0f / (4.0f * t[c]);
    float g[KS];
#pragma unroll
    for (int j = 0; j < KS; ++j) {
        const float z = -2.0f + (float)j * (5.0f / 6.0f);
        g[j] = -(z * z) * s;
    }

    const int wo0     = k * TW;          // first output col
    const int ho0     = tyv * TH;        // first output row
    const int colbase = 2 * wo0 - 4;     // window cols [colbase, colbase+15]
    const int ibase   = 2 * ho0 - 3;     // input rows [ibase, ibase+NROWS-1]

    const float  NEG = -INFINITY;
    const float4 N4  = make_float4(NEG, NEG, NEG, NEG);

    const float* __restrict__ plane = f + (b * C_CH + c) * (H_IN * W_IN);
    float* __restrict__ obase =
        out + ((b * C_CH + c) * H_OUT + ho0) * W_OUT + wo0;

    // Per-lane safe sub-offsets for the two possibly-OOB float4s.
    const bool kzero = (k == 0);          // cols -4..-1 invalid -> a0 = -inf
    const bool klast = (k == KX - 1);     // cols 224..227 invalid -> a3 = -inf
    const int  off0  = kzero ? 4 : 0;     // clamped, aligned, in-bounds addr
    const int  off3  = klast ? 8 : 12;

    float acc[TH][TW];
#pragma unroll
    for (int d = 0; d < TH; ++d)
#pragma unroll
        for (int m = 0; m < TW; ++m) acc[d][m] = NEG;

#pragma unroll
    for (int r = 0; r < NROWS; ++r) {      // fully unrolled: all indices static
        const int  i     = ibase + r;
        const bool rowok = (i >= 0) && (i < H_IN);
        const int  isafe = rowok ? i : 0;  // safe row for masked-out loads
        const float* rb  = plane + isafe * W_IN + colbase;

        float4 a0 = *(const float4*)(rb + off0);
        float4 a1 = *(const float4*)(rb + 4);
        float4 a2 = *(const float4*)(rb + 8);
        float4 a3 = *(const float4*)(rb + off3);
        if (kzero) a0 = N4;                // cndmask fixups, no divergent path
        if (klast) a3 = N4;

        const float v[16] = {a0.x,a0.y,a0.z,a0.w, a1.x,a1.y,a1.z,a1.w,
                             a2.x,a2.y,a2.z,a2.w, a3.x,a3.y,a3.z,a3.w};

        // Horizontal max-plus: rm[m] = max_j( v[2m+1+j] + g[j] ), j=0..6
        float rm[TW];
#pragma unroll
        for (int m = 0; m < TW; ++m) {
            float x =    v[2*m + 1] + g[0];
            x = fmaxf(x, v[2*m + 2] + g[1]);
            x = fmaxf(x, v[2*m + 3] + g[2]);
            x = fmaxf(x, v[2*m + 4] + g[3]);
            x = fmaxf(x, v[2*m + 5] + g[4]);
            x = fmaxf(x, v[2*m + 6] + g[5]);
            x = fmaxf(x, v[2*m + 7] + g[6]);
            rm[m] = rowok ? x : NEG;       // -inf row: updates become no-ops
        }

        // Vertical rolling update: output row d uses ki = r - 2d in [0,6].
#pragma unroll
        for (int d = 0; d < TH; ++d) {
            if (r >= 2 * d && r <= 2 * d + 6) {
#pragma unroll
                for (int m = 0; m < TW; ++m)
                    acc[d][m] = fmaxf(acc[d][m], rm[m] + g[r - 2 * d]);
            }
        }

        // Row d is complete after r = 2d+6 -> emit (spreads stores, frees acc).
        if (r >= 6 && ((r - 6) & 1) == 0) {
            const int d = (r - 6) / 2;     // compile-time constant after unroll
            *(float4*)(obase + d * W_OUT) =
                make_float4(acc[d][0], acc[d][1], acc[d][2], acc[d][3]);
        }
    }
}

extern "C" void kernel_launch(void* const* d_in, const int* in_sizes, int n_in,
                              void* d_out, int out_size, void* d_ws, size_t ws_size,
                              hipStream_t stream) {
    const float* f = (const float*)d_in[0];   // [16, 96, 224, 224] f32
    const float* t = (const float*)d_in[1];   // [96] f32
    float* out = (float*)d_out;               // [16, 96, 112, 112] f32

    const int total   = B_SZ * C_CH * KYV * KX;  // 301,056 threads
    const int threads = 256;
    const int blocks  = total / threads;         // 1176, exact
    parab_pool2d_kernel<<<blocks, threads, 0, stream>>>(f, t, out);
}

// Round 7
// 80.159 us; speedup vs baseline: 1.2045x; 1.2045x over previous
//
#include <hip/hip_runtime.h>
#include <math.h>

// ParabolicPool2D: morphological dilation (max-plus pool), KS=7, STRIDE=2, pad=3.
// Separable in max-plus: h[c,ki,kj] = g[c,ki] + g[c,kj], g[c,j] = -z_j^2/(4 t_c),
// z = linspace(-2, 3, 7)  =>  out = max_ki( max_kj(f + g_kj) + g_ki ).
//
// R7: wave-per-strip, shuffle-based horizontal halo.
//  - One WAVE owns a full-width strip: 112 output cols x TH=16 output rows.
//    Lane L (0..55) handles output cols {2L, 2L+1}; lanes 56..63 clamped+masked.
//  - Per input row, lane loads ONE float4 (input cols 4L..4L+3): a wave's row
//    read is 896 B dense & coalesced (R4/R5 loaded 4 overlapping float4/lane).
//    The 9-col window comes from 3x shfl_up + 2x shfl_down (register routing).
//  - Rolling vertical max-plus window over 37 input rows -> overfetch 37/32 =
//    1.156x (R5: 1.31x), but UNLIKE R6 the thread count stays at 602K active
//    (10,752 waves = 10.5/SIMD demanded) and VGPR is uncapped — R6's regression
//    was occupancy/VGPR-cap, not the overfetch model.

#define KS     7
#define C_CH   96
#define B_SZ   16
#define H_IN   224
#define W_IN   224
#define H_OUT  112
#define W_OUT  112
#define TH     16                    // output rows per wave-strip
#define KYV    (H_OUT / TH)          // 7 strips per plane
#define NROWS  (2 * TH + 5)          // 37 input rows per strip
#define NWAVES (B_SZ * C_CH * KYV)   // 10,752 waves

__global__ __launch_bounds__(256)
void parab_pool2d_kernel(const float* __restrict__ f,
                         const float* __restrict__ t,
                         float* __restrict__ out)
{
    const int lane = threadIdx.x & 63;
    const int wave = blockIdx.x * 4 + (threadIdx.x >> 6);

    const int tyv  = wave % KYV;
    const int rest = wave / KYV;
    const int c    = rest % C_CH;
    const int b    = rest / C_CH;

    // g[j] = -z_j^2 / (4 t_c),  z = -2 + j*(5/6)
    const float s = 1.0f / (4.0f * t[c]);
    float g[KS];
#pragma unroll
    for (int j = 0; j < KS; ++j) {
        const float z = -2.0f + (float)j * (5.0f / 6.0f);
        g[j] = -(z * z) * s;
    }

    const int ho0   = tyv * TH;
    const int ibase = 2 * ho0 - 3;            // rows [ibase, ibase+36]

    const bool active = (lane < 56);
    const bool l0     = (lane == 0);          // left halo cols -3..-1 OOB
    const bool l55    = (lane == 55);         // right halo cols 224,225 OOB
    const int  colL   = active ? 4 * lane : 220;   // clamped safe col base

    const float NEG = -INFINITY;
    const float* __restrict__ plane = f + (b * C_CH + c) * (H_IN * W_IN);
    float* __restrict__ obase =
        out + ((b * C_CH + c) * H_OUT + ho0) * W_OUT + 2 * lane;

    float acc[TH][2];
#pragma unroll
    for (int d = 0; d < TH; ++d) { acc[d][0] = NEG; acc[d][1] = NEG; }

#pragma unroll
    for (int r = 0; r < NROWS; ++r) {          // fully unrolled, static indexing
        const int  i     = ibase + r;
        const bool rowok = (i >= 0) && (i < H_IN);
        const int  isafe = rowok ? i : 0;

        const float4 o = *(const float4*)(plane + isafe * W_IN + colL);

        // Halo via cross-lane routing (ds_bpermute), not extra loads.
        float ly = __shfl_up(o.y, 1);          // col 4L-3
        float lz = __shfl_up(o.z, 1);          // col 4L-2
        float lw = __shfl_up(o.w, 1);          // col 4L-1
        float rx = __shfl_down(o.x, 1);        // col 4L+4
        float ry = __shfl_down(o.y, 1);        // col 4L+5
        if (l0)  { ly = NEG; lz = NEG; lw = NEG; }
        if (l55) { rx = NEG; ry = NEG; }

        // rm0: output col 2L   <- input cols 4L-3 .. 4L+3
        float rm0 =        ly  + g[0];
        rm0 = fmaxf(rm0,   lz  + g[1]);
        rm0 = fmaxf(rm0,   lw  + g[2]);
        rm0 = fmaxf(rm0,   o.x + g[3]);
        rm0 = fmaxf(rm0,   o.y + g[4]);
        rm0 = fmaxf(rm0,   o.z + g[5]);
        rm0 = fmaxf(rm0,   o.w + g[6]);
        // rm1: output col 2L+1 <- input cols 4L-1 .. 4L+5
        float rm1 =        lw  + g[0];
        rm1 = fmaxf(rm1,   o.x + g[1]);
        rm1 = fmaxf(rm1,   o.y + g[2]);
        rm1 = fmaxf(rm1,   o.z + g[3]);
        rm1 = fmaxf(rm1,   o.w + g[4]);
        rm1 = fmaxf(rm1,   rx  + g[5]);
        rm1 = fmaxf(rm1,   ry  + g[6]);
        if (!rowok) { rm0 = NEG; rm1 = NEG; }  // -inf row: updates are no-ops

        // Vertical rolling update: output row d uses ki = r - 2d in [0,6]
        // (at most 4 rows live at any r -> acc liveness doesn't grow with TH).
#pragma unroll
        for (int d = 0; d < TH; ++d) {
            if (r >= 2 * d && r <= 2 * d + 6) {
                acc[d][0] = fmaxf(acc[d][0], rm0 + g[r - 2 * d]);
                acc[d][1] = fmaxf(acc[d][1], rm1 + g[r - 2 * d]);
            }
        }

        // Row d completes at r = 2d+6 -> emit, freeing its registers.
        if (r >= 6 && ((r - 6) & 1) == 0) {
            const int d = (r - 6) / 2;         // compile-time after unroll
            if (active)
                *(float2*)(obase + d * W_OUT) = make_float2(acc[d][0], acc[d][1]);
        }
    }
}

extern "C" void kernel_launch(void* const* d_in, const int* in_sizes, int n_in,
                              void* d_out, int out_size, void* d_ws, size_t ws_size,
                              hipStream_t stream) {
    const float* f = (const float*)d_in[0];   // [16, 96, 224, 224] f32
    const float* t = (const float*)d_in[1];   // [96] f32
    float* out = (float*)d_out;               // [16, 96, 112, 112] f32

    const int threads = 256;                  // 4 waves per block
    const int blocks  = NWAVES / 4;           // 2688, exact
    parab_pool2d_kernel<<<blocks, threads, 0, stream>>>(f, t, out);
}